// Round 9
// baseline (2852.236 us; speedup 1.0000x reference)
//
#include <hip/hip_runtime.h>

#define Bsz   1024
#define Tlen  512
#define VOC   8
#define EDIM  32
#define HDIM  64
#define G4    256
#define SEQB  4                  // sequences per block/pair, A-rows {0,4,8,12}
#define NBLK  (Bsz / SEQB)       // 256 pairs

// split-kernel ring/flag geometry (in d_ws)
#define RDEP   16                // ring slots (steps) per pair
#define RMASK  (RDEP - 1)
#define RING_BASE  16384                     // bytes; table region is [0, 9216)
#define PAIR_BYTES (RDEP * 2048)             // 16 slots x 1024 f16
#define NPAIR  256
#define FLAG_BASE  (RING_BASE + NPAIR * PAIR_BYTES)
#define WS_NEED    ((size_t)FLAG_BASE + 4096)

typedef _Float16 f16x8 __attribute__((ext_vector_type(8)));
typedef float    f32x4 __attribute__((ext_vector_type(4)));
typedef unsigned long long u64;
typedef u64 u64x2 __attribute__((ext_vector_type(2)));

__device__ __forceinline__ float ex2(float x) {
#if __has_builtin(__builtin_amdgcn_exp2f)
    return __builtin_amdgcn_exp2f(x);
#else
    return exp2f(x);
#endif
}
__device__ __forceinline__ float rcp_(float x) {
#if __has_builtin(__builtin_amdgcn_rcpf)
    return __builtin_amdgcn_rcpf(x);
#else
    return 1.0f / x;
#endif
}

// paired-rcp LSTM cell update (identical numerics to R6/R7)
__device__ __forceinline__ void cell_upd(float ai, float af, float ag, float ao,
                                         float& c, float& h) {
    const float K1 = 1.4426950408889634f;
    float ei = ex2(fminf(-K1 * ai, 60.0f));
    float ef = ex2(fminf(-K1 * af, 60.0f));
    float eg = ex2(fminf(-2.0f * K1 * ag, 60.0f));
    float eo = ex2(fminf(-K1 * ao, 60.0f));
    float di = 1.0f + ei, df = 1.0f + ef, dg = 1.0f + eg, dn = 1.0f + eo;
    float r1 = rcp_(di * df);
    float si = df * r1;
    float sf = di * r1;
    float r2 = rcp_(dg * dn);
    float tg = __builtin_fmaf(2.0f * dn, r2, -1.0f);
    float so = dg * r2;
    c = sf * c + si * tg;
    float ec = ex2(fminf(-2.0f * K1 * c, 60.0f));
    h = so * __builtin_fmaf(2.0f, rcp_(1.0f + ec), -1.0f);
}

// ws: [0 .. 2048) packed layer0 gate table: float4{i,f,g,o}[voc][hcol]
//     [2048 .. 2304) bih1+bhh1 (gate index 64q+c)
__global__ void precompute_kernel(const float* __restrict__ emb,
                                  const float* __restrict__ Wih0,
                                  const float* __restrict__ bih0,
                                  const float* __restrict__ bhh0,
                                  const float* __restrict__ bih1,
                                  const float* __restrict__ bhh1,
                                  float* __restrict__ ws) {
    int g = threadIdx.x;
    int v = blockIdx.x;
    if (v < VOC) {
        float acc = bih0[g] + bhh0[g];
        #pragma unroll
        for (int e = 0; e < EDIM; ++e)
            acc += Wih0[g * EDIM + e] * emb[v * EDIM + e];
        const int q = g >> 6, c = g & 63;
        ws[(v * 64 + c) * 4 + q] = acc;
    } else {
        ws[VOC * G4 + g] = bih1[g] + bhh1[g];
    }
}

// h LDS/ring layout = A-fragment order for mfma_f32_16x16x32_f16 (validated R4/R7):
__device__ __forceinline__ f16x8 read_h_frag(const _Float16* hb, int kc, int l) {
    int off = kc * 512 + ((l * 8) ^ ((l & 3) << 7));
    return *(const f16x8*)(hb + off);
}
__device__ __forceinline__ void write_h(_Float16* hb, int r, int c, float v) {
    int off = (c >> 5) * 512 +
              (((((c & 31) >> 3) * 128) + r * 8 + (c & 7)) ^ ((r & 3) << 7));
    hb[off] = (_Float16)v;
}

// device-coherent (agent scope) flag/data ops
__device__ __forceinline__ int aload(const int* p) {
    return __hip_atomic_load(p, __ATOMIC_RELAXED, __HIP_MEMORY_SCOPE_AGENT);
}
__device__ __forceinline__ void astore(int* p, int v) {
    __hip_atomic_store(p, v, __ATOMIC_RELAXED, __HIP_MEMORY_SCOPE_AGENT);
}
__device__ __forceinline__ f16x8 ald16(const _Float16* ptr) {   // coherent 16B read as 2x8B
    u64 lo = __hip_atomic_load((const u64*)ptr,       __ATOMIC_RELAXED, __HIP_MEMORY_SCOPE_AGENT);
    u64 hi = __hip_atomic_load(((const u64*)ptr) + 1, __ATOMIC_RELAXED, __HIP_MEMORY_SCOPE_AGENT);
    u64x2 v; v[0] = lo; v[1] = hi;
    return __builtin_bit_cast(f16x8, v);
}

#define POLL(var, ptr, needv)                                                   \
    { int gc_ = 0;                                                              \
      while ((var) < (needv)) {                                                 \
          (var) = aload(ptr);                                                   \
          if ((var) < (needv)) { if (++gc_ > 20000000) break;                   \
                                 __builtin_amdgcn_s_sleep(4); } } }

// ---------------- split kernel: even blocks = layer0, odd blocks = layer1 ----------------
__global__ __launch_bounds__(256, 2)
void lstm_split(const int*   __restrict__ x,
                const float* __restrict__ Whh0,
                const float* __restrict__ Wih1,
                const float* __restrict__ Whh1,
                const float* __restrict__ Wfc,
                const float* __restrict__ bfc,
                float* __restrict__ ws,
                float* __restrict__ out) {
    __shared__ float4    stbl4[VOC * 64];        // L0 only
    __shared__ int       sxl[SEQB * Tlen];       // L0 only
    __shared__ _Float16  hb[2][1024];            // h double buffer (own layer)
    __shared__ float     sh1f[SEQB][HDIM + 1];   // L1 only

    const int tid  = threadIdx.x;
    const int bid  = blockIdx.x;
    const int p    = bid >> 1;
    const bool isL1 = bid & 1;
    const int b0   = p * SEQB;
    const int l    = tid & 63;
    const int w    = tid >> 6;                   // 4 waves = 4 col blocks
    const int l15  = l & 15;
    const int kb   = (l >> 4) * 8;
    const int cq0  = 16 * w + l15;
    const int s    = l >> 4;
    const int r4   = 4 * s;
    // swizzled element offset for (r4, cq0); r4&3==0 so the XOR term vanishes
    const int so   = (cq0 >> 5) * 512 + ((cq0 & 31) >> 3) * 128 + r4 * 8 + (cq0 & 7);

    char* wsb = (char*)ws;
    _Float16* ring = (_Float16*)(wsb + RING_BASE + p * PAIR_BYTES);
    int* f0 = (int*)(wsb + FLAG_BASE) + p;              // L0 progress (h0 published)
    int* f1 = (int*)(wsb + FLAG_BASE + 2048) + p;       // L1 progress (ring consumption)

    for (int i = tid; i < 2048; i += 256) ((_Float16*)hb)[i] = (_Float16)0.0f;

    if (!isL1) {
        // ================= layer-0 producer block =================
        for (int i = tid; i < VOC * 64; i += 256) stbl4[i] = ((const float4*)ws)[i];
        for (int i = tid; i < SEQB * Tlen; i += 256) sxl[i] = x[b0 * Tlen + i];
        for (int i = tid; i < RDEP * 1024; i += 256) ring[i] = (_Float16)0.0f;

        f16x8 wA0[4], wA1[4];
        #pragma unroll
        for (int q = 0; q < 4; ++q) {
            const int cq = 64 * q + cq0;
            const float* p0 = Whh0 + cq * HDIM + kb;
            const float* p1 = Whh0 + cq * HDIM + 32 + kb;
            #pragma unroll
            for (int i = 0; i < 8; ++i) { wA0[q][i] = (_Float16)p0[i]; wA1[q][i] = (_Float16)p1[i]; }
        }
        __syncthreads();

        float cst = 0.0f;
        int tc = sxl[s * Tlen];
        int kf1 = 0;
        #pragma unroll 1
        for (int t = 0; t < Tlen; ++t) {
            if ((t & 3) == 0 && t > 8) {            // ring-reuse throttle, amortized
                const int need = t - 8;
                if (kf1 < need) POLL(kf1, f1, need);
            }
            const _Float16* h0b = hb[(t + 1) & 1];
            f16x8 a0 = read_h_frag(h0b, 0, l);
            f16x8 a1 = read_h_frag(h0b, 1, l);
            f32x4 tq = *(const f32x4*)&stbl4[tc * 64 + cq0];
            f32x4 acc0 = (f32x4)(0.0f), acc1 = (f32x4)(0.0f);
            f32x4 acc2 = (f32x4)(0.0f), acc3 = (f32x4)(0.0f);
            acc0 = __builtin_amdgcn_mfma_f32_16x16x32_f16(a0, wA0[0], acc0, 0, 0, 0);
            acc1 = __builtin_amdgcn_mfma_f32_16x16x32_f16(a0, wA0[1], acc1, 0, 0, 0);
            acc2 = __builtin_amdgcn_mfma_f32_16x16x32_f16(a0, wA0[2], acc2, 0, 0, 0);
            acc3 = __builtin_amdgcn_mfma_f32_16x16x32_f16(a0, wA0[3], acc3, 0, 0, 0);
            acc0 = __builtin_amdgcn_mfma_f32_16x16x32_f16(a1, wA1[0], acc0, 0, 0, 0);
            acc1 = __builtin_amdgcn_mfma_f32_16x16x32_f16(a1, wA1[1], acc1, 0, 0, 0);
            acc2 = __builtin_amdgcn_mfma_f32_16x16x32_f16(a1, wA1[2], acc2, 0, 0, 0);
            acc3 = __builtin_amdgcn_mfma_f32_16x16x32_f16(a1, wA1[3], acc3, 0, 0, 0);

            const int kn = (t + 1 < Tlen) ? (t + 1) : (Tlen - 1);
            const int tnext = sxl[s * Tlen + kn];

            float ai = acc0[0] + tq[0];
            float af = acc1[0] + tq[1];
            float ag = acc2[0] + tq[2];
            float ao = acc3[0] + tq[3];
            float hv;
            cell_upd(ai, af, ag, ao, cst, hv);
            hb[t & 1][so] = (_Float16)hv;                       // LDS for own recurrence
            ring[(t & RMASK) * 1024 + so] = (_Float16)hv;       // global for consumer

            if ((t & 3) == 3) asm volatile("s_waitcnt vmcnt(0)" ::: "memory"); // stores done before publish
            asm volatile("s_waitcnt lgkmcnt(0)" ::: "memory");
            __builtin_amdgcn_s_barrier();
            __builtin_amdgcn_sched_barrier(0);
            if ((t & 3) == 3 && tid == 0) { __threadfence(); astore(f0, t + 1); }
            tc = tnext;
        }
    } else {
        // ================= layer-1 consumer block =================
        f16x8 wI0[4], wI1[4], wH0[4], wH1[4];
        float b1s[4];
        #pragma unroll
        for (int q = 0; q < 4; ++q) {
            const int cq = 64 * q + cq0;
            b1s[q] = ws[VOC * G4 + cq];
            const float* pi0 = Wih1 + cq * HDIM + kb;
            const float* pi1 = Wih1 + cq * HDIM + 32 + kb;
            const float* ph0 = Whh1 + cq * HDIM + kb;
            const float* ph1 = Whh1 + cq * HDIM + 32 + kb;
            #pragma unroll
            for (int i = 0; i < 8; ++i) {
                wI0[q][i] = (_Float16)pi0[i]; wI1[q][i] = (_Float16)pi1[i];
                wH0[q][i] = (_Float16)ph0[i]; wH1[q][i] = (_Float16)ph1[i];
            }
        }
        __syncthreads();

        float cst = 0.0f;
        int kf0 = 0;
        POLL(kf0, f0, 4);                         // first producer publish covers slots 0..3
        const int eo0 = (l * 8) ^ ((l & 3) << 7);
        const int eo1 = 512 + eo0;
        f16x8 cA0 = ald16(ring + eo0),        cA1 = ald16(ring + eo1);         // h0(0)
        f16x8 nA0 = ald16(ring + 1024 + eo0), nA1 = ald16(ring + 1024 + eo1);  // h0(1)
        f16x8 mA0 = ald16(ring + 2048 + eo0), mA1 = ald16(ring + 2048 + eo1);  // h0(2)

        #pragma unroll 1
        for (int u = 0; u < Tlen; ++u) {
            if (u + 4 <= Tlen && kf0 < u + 4) POLL(kf0, f0, u + 4);
            const _Float16* h1p = hb[(u + 1) & 1];
            f16x8 b0f = read_h_frag(h1p, 0, l);
            f16x8 b1f = read_h_frag(h1p, 1, l);
            f16x8 fA0, fA1;                        // prefetch h0(u+3), 3-deep pipeline
            if (u + 3 < Tlen) {
                const int base = ((u + 3) & RMASK) * 1024;
                fA0 = ald16(ring + base + eo0);
                fA1 = ald16(ring + base + eo1);
            } else { fA0 = mA0; fA1 = mA1; }

            f32x4 acc0 = (f32x4)(0.0f), acc1 = (f32x4)(0.0f);
            f32x4 acc2 = (f32x4)(0.0f), acc3 = (f32x4)(0.0f);
            acc0 = __builtin_amdgcn_mfma_f32_16x16x32_f16(cA0, wI0[0], acc0, 0, 0, 0);
            acc1 = __builtin_amdgcn_mfma_f32_16x16x32_f16(cA0, wI0[1], acc1, 0, 0, 0);
            acc2 = __builtin_amdgcn_mfma_f32_16x16x32_f16(cA0, wI0[2], acc2, 0, 0, 0);
            acc3 = __builtin_amdgcn_mfma_f32_16x16x32_f16(cA0, wI0[3], acc3, 0, 0, 0);
            acc0 = __builtin_amdgcn_mfma_f32_16x16x32_f16(cA1, wI1[0], acc0, 0, 0, 0);
            acc1 = __builtin_amdgcn_mfma_f32_16x16x32_f16(cA1, wI1[1], acc1, 0, 0, 0);
            acc2 = __builtin_amdgcn_mfma_f32_16x16x32_f16(cA1, wI1[2], acc2, 0, 0, 0);
            acc3 = __builtin_amdgcn_mfma_f32_16x16x32_f16(cA1, wI1[3], acc3, 0, 0, 0);
            acc0 = __builtin_amdgcn_mfma_f32_16x16x32_f16(b0f, wH0[0], acc0, 0, 0, 0);
            acc1 = __builtin_amdgcn_mfma_f32_16x16x32_f16(b0f, wH0[1], acc1, 0, 0, 0);
            acc2 = __builtin_amdgcn_mfma_f32_16x16x32_f16(b0f, wH0[2], acc2, 0, 0, 0);
            acc3 = __builtin_amdgcn_mfma_f32_16x16x32_f16(b0f, wH0[3], acc3, 0, 0, 0);
            acc0 = __builtin_amdgcn_mfma_f32_16x16x32_f16(b1f, wH1[0], acc0, 0, 0, 0);
            acc1 = __builtin_amdgcn_mfma_f32_16x16x32_f16(b1f, wH1[1], acc1, 0, 0, 0);
            acc2 = __builtin_amdgcn_mfma_f32_16x16x32_f16(b1f, wH1[2], acc2, 0, 0, 0);
            acc3 = __builtin_amdgcn_mfma_f32_16x16x32_f16(b1f, wH1[3], acc3, 0, 0, 0);

            float ai = acc0[0] + b1s[0];
            float af = acc1[0] + b1s[1];
            float ag = acc2[0] + b1s[2];
            float ao = acc3[0] + b1s[3];
            float hv;
            cell_upd(ai, af, ag, ao, cst, hv);
            if (u < Tlen - 1) hb[u & 1][so] = (_Float16)hv;
            else              sh1f[s][cq0] = hv;

            asm volatile("s_waitcnt lgkmcnt(0)" ::: "memory");
            __builtin_amdgcn_s_barrier();
            __builtin_amdgcn_sched_barrier(0);
            if ((u & 3) == 3 && tid == 0) astore(f1, u + 1);
            cA0 = nA0; cA1 = nA1; nA0 = mA0; nA1 = mA1; mA0 = fA0; mA1 = fA1;
        }
        __syncthreads();
        if (tid < SEQB * VOC) {
            const int seq = tid >> 3, v = tid & 7;
            float acc2 = bfc[v];
            #pragma unroll
            for (int j = 0; j < HDIM; ++j)
                acc2 += Wfc[v * HDIM + j] * sh1f[seq][j];
            out[(b0 + seq) * VOC + v] = acc2;
        }
    }
}

// ---------------- fallback: validated R7 single-kernel (222 us) ----------------
__global__ __launch_bounds__(512)
void lstm_fb(const int*   __restrict__ x,
             const float* __restrict__ Whh0,
             const float* __restrict__ Wih1,
             const float* __restrict__ Whh1,
             const float* __restrict__ Wfc,
             const float* __restrict__ bfc,
             const float* __restrict__ ws,
             float* __restrict__ out) {
    __shared__ float4    stbl4[VOC * 64];
    __shared__ int       sxl[SEQB * Tlen];
    __shared__ _Float16  hbuf[2][2][1024];
    __shared__ float     sh1f[SEQB][HDIM + 1];

    const int tid  = threadIdx.x;
    const int b0   = blockIdx.x * SEQB;
    const int l    = tid & 63;
    const int wid  = tid >> 6;
    const bool isL1 = (wid >= 4);
    const int w    = wid & 3;
    const int l15  = l & 15;
    const int kb   = (l >> 4) * 8;
    const int cq0  = 16 * w + l15;
    const int s    = l >> 4;
    const int r4   = 4 * s;

    for (int i = tid; i < VOC * 64; i += 512) stbl4[i] = ((const float4*)ws)[i];
    for (int i = tid; i < SEQB * Tlen; i += 512) sxl[i] = x[b0 * Tlen + i];
    for (int i = tid; i < 2 * 2 * 1024; i += 512) ((_Float16*)hbuf)[i] = (_Float16)0.0f;

    f16x8 wA0[4], wA1[4], wI0[4], wI1[4], wH0[4], wH1[4];
    float b1s[4];
    if (!isL1) {
        #pragma unroll
        for (int q = 0; q < 4; ++q) {
            const int cq = 64 * q + cq0;
            const float* p0 = Whh0 + cq * HDIM + kb;
            const float* p1 = Whh0 + cq * HDIM + 32 + kb;
            #pragma unroll
            for (int i = 0; i < 8; ++i) { wA0[q][i] = (_Float16)p0[i]; wA1[q][i] = (_Float16)p1[i]; }
        }
    } else {
        #pragma unroll
        for (int q = 0; q < 4; ++q) {
            const int cq = 64 * q + cq0;
            b1s[q] = ws[VOC * G4 + cq];
            const float* pi0 = Wih1 + cq * HDIM + kb;
            const float* pi1 = Wih1 + cq * HDIM + 32 + kb;
            const float* ph0 = Whh1 + cq * HDIM + kb;
            const float* ph1 = Whh1 + cq * HDIM + 32 + kb;
            #pragma unroll
            for (int i = 0; i < 8; ++i) {
                wI0[q][i] = (_Float16)pi0[i]; wI1[q][i] = (_Float16)pi1[i];
                wH0[q][i] = (_Float16)ph0[i]; wH1[q][i] = (_Float16)ph1[i];
            }
        }
    }

    float cst = 0.0f;
    __syncthreads();
    int tc = 0;
    if (!isL1) tc = sxl[s * Tlen];

    #pragma unroll 1
    for (int k = 0; k <= Tlen; ++k) {
        const int cur = k & 1, nxt = cur ^ 1;
        const _Float16* h0b = hbuf[cur][0];
        f16x8 a0 = read_h_frag(h0b, 0, l);
        f16x8 a1 = read_h_frag(h0b, 1, l);

        if (!isL1) {
            f32x4 tq = *(const f32x4*)&stbl4[tc * 64 + cq0];
            f32x4 acc0 = (f32x4)(0.0f), acc1 = (f32x4)(0.0f);
            f32x4 acc2 = (f32x4)(0.0f), acc3 = (f32x4)(0.0f);
            acc0 = __builtin_amdgcn_mfma_f32_16x16x32_f16(a0, wA0[0], acc0, 0, 0, 0);
            acc1 = __builtin_amdgcn_mfma_f32_16x16x32_f16(a0, wA0[1], acc1, 0, 0, 0);
            acc2 = __builtin_amdgcn_mfma_f32_16x16x32_f16(a0, wA0[2], acc2, 0, 0, 0);
            acc3 = __builtin_amdgcn_mfma_f32_16x16x32_f16(a0, wA0[3], acc3, 0, 0, 0);
            acc0 = __builtin_amdgcn_mfma_f32_16x16x32_f16(a1, wA1[0], acc0, 0, 0, 0);
            acc1 = __builtin_amdgcn_mfma_f32_16x16x32_f16(a1, wA1[1], acc1, 0, 0, 0);
            acc2 = __builtin_amdgcn_mfma_f32_16x16x32_f16(a1, wA1[2], acc2, 0, 0, 0);
            acc3 = __builtin_amdgcn_mfma_f32_16x16x32_f16(a1, wA1[3], acc3, 0, 0, 0);
            const int kn = (k + 1 < Tlen) ? (k + 1) : (Tlen - 1);
            const int tnext = sxl[s * Tlen + kn];
            if (k < Tlen) {
                float ai = acc0[0] + tq[0];
                float af = acc1[0] + tq[1];
                float ag = acc2[0] + tq[2];
                float ao = acc3[0] + tq[3];
                float hv;
                cell_upd(ai, af, ag, ao, cst, hv);
                write_h(hbuf[nxt][0], r4, cq0, hv);
            }
            tc = tnext;
        } else {
            const _Float16* h1b = hbuf[cur][1];
            f16x8 b0f = read_h_frag(h1b, 0, l);
            f16x8 b1f = read_h_frag(h1b, 1, l);
            f32x4 acc0 = (f32x4)(0.0f), acc1 = (f32x4)(0.0f);
            f32x4 acc2 = (f32x4)(0.0f), acc3 = (f32x4)(0.0f);
            acc0 = __builtin_amdgcn_mfma_f32_16x16x32_f16(a0,  wI0[0], acc0, 0, 0, 0);
            acc1 = __builtin_amdgcn_mfma_f32_16x16x32_f16(a0,  wI0[1], acc1, 0, 0, 0);
            acc2 = __builtin_amdgcn_mfma_f32_16x16x32_f16(a0,  wI0[2], acc2, 0, 0, 0);
            acc3 = __builtin_amdgcn_mfma_f32_16x16x32_f16(a0,  wI0[3], acc3, 0, 0, 0);
            acc0 = __builtin_amdgcn_mfma_f32_16x16x32_f16(a1,  wI1[0], acc0, 0, 0, 0);
            acc1 = __builtin_amdgcn_mfma_f32_16x16x32_f16(a1,  wI1[1], acc1, 0, 0, 0);
            acc2 = __builtin_amdgcn_mfma_f32_16x16x32_f16(a1,  wI1[2], acc2, 0, 0, 0);
            acc3 = __builtin_amdgcn_mfma_f32_16x16x32_f16(a1,  wI1[3], acc3, 0, 0, 0);
            acc0 = __builtin_amdgcn_mfma_f32_16x16x32_f16(b0f, wH0[0], acc0, 0, 0, 0);
            acc1 = __builtin_amdgcn_mfma_f32_16x16x32_f16(b0f, wH0[1], acc1, 0, 0, 0);
            acc2 = __builtin_amdgcn_mfma_f32_16x16x32_f16(b0f, wH0[2], acc2, 0, 0, 0);
            acc3 = __builtin_amdgcn_mfma_f32_16x16x32_f16(b0f, wH0[3], acc3, 0, 0, 0);
            acc0 = __builtin_amdgcn_mfma_f32_16x16x32_f16(b1f, wH1[0], acc0, 0, 0, 0);
            acc1 = __builtin_amdgcn_mfma_f32_16x16x32_f16(b1f, wH1[1], acc1, 0, 0, 0);
            acc2 = __builtin_amdgcn_mfma_f32_16x16x32_f16(b1f, wH1[2], acc2, 0, 0, 0);
            acc3 = __builtin_amdgcn_mfma_f32_16x16x32_f16(b1f, wH1[3], acc3, 0, 0, 0);
            if (k >= 1) {
                float ai = acc0[0] + b1s[0];
                float af = acc1[0] + b1s[1];
                float ag = acc2[0] + b1s[2];
                float ao = acc3[0] + b1s[3];
                float hv;
                cell_upd(ai, af, ag, ao, cst, hv);
                if (k == Tlen) sh1f[s][cq0] = hv;
                else           write_h(hbuf[nxt][1], r4, cq0, hv);
            }
        }
        __syncthreads();
    }

    if (tid < SEQB * VOC) {
        const int seq = tid >> 3, v = tid & 7;
        float acc2 = bfc[v];
        #pragma unroll
        for (int j = 0; j < HDIM; ++j)
            acc2 += Wfc[v * HDIM + j] * sh1f[seq][j];
        out[(b0 + seq) * VOC + v] = acc2;
    }
}

extern "C" void kernel_launch(void* const* d_in, const int* in_sizes, int n_in,
                              void* d_out, int out_size, void* d_ws, size_t ws_size,
                              hipStream_t stream) {
    const int*   x    = (const int*)  d_in[0];
    const float* emb  = (const float*)d_in[1];
    const float* Wih0 = (const float*)d_in[2];
    const float* Whh0 = (const float*)d_in[3];
    const float* bih0 = (const float*)d_in[4];
    const float* bhh0 = (const float*)d_in[5];
    const float* Wih1 = (const float*)d_in[6];
    const float* Whh1 = (const float*)d_in[7];
    const float* bih1 = (const float*)d_in[8];
    const float* bhh1 = (const float*)d_in[9];
    const float* Wfc  = (const float*)d_in[10];
    const float* bfc  = (const float*)d_in[11];
    float* out = (float*)d_out;
    float* ws  = (float*)d_ws;

    hipLaunchKernelGGL(precompute_kernel, dim3(VOC + 1), dim3(G4), 0, stream,
                       emb, Wih0, bih0, bhh0, bih1, bhh1, ws);
    if (ws_size >= WS_NEED) {
        hipMemsetAsync((char*)d_ws + FLAG_BASE, 0, 4096, stream);
        hipLaunchKernelGGL(lstm_split, dim3(2 * NPAIR), dim3(256), 0, stream,
                           x, Whh0, Wih1, Whh1, Wfc, bfc, ws, out);
    } else {
        hipLaunchKernelGGL(lstm_fb, dim3(NBLK), dim3(512), 0, stream,
                           x, Whh0, Wih1, Whh1, Wfc, bfc, ws, out);
    }
}

// Round 10
// 373.700 us; speedup vs baseline: 7.6324x; 7.6324x over previous
//
#include <hip/hip_runtime.h>

#define Bsz   1024
#define Tlen  512
#define VOC   8
#define EDIM  32
#define HDIM  64
#define G4    256
#define SEQB  2                  // sequences per block, mapped to A-rows {0,4}
#define NT    512                // 8 waves: 0-3 layer0, 4-7 layer1
#define NBLK  (Bsz / SEQB)       // 512 blocks -> 2 blocks/CU

typedef _Float16 f16x8 __attribute__((ext_vector_type(8)));
typedef float    f32x4 __attribute__((ext_vector_type(4)));

__device__ __forceinline__ float ex2(float x) {
#if __has_builtin(__builtin_amdgcn_exp2f)
    return __builtin_amdgcn_exp2f(x);
#else
    return exp2f(x);
#endif
}
__device__ __forceinline__ float rcp_(float x) {
#if __has_builtin(__builtin_amdgcn_rcpf)
    return __builtin_amdgcn_rcpf(x);
#else
    return 1.0f / x;
#endif
}

// paired-rcp LSTM cell update (identical numerics to R6/R7): 5 exp2 + 3 rcp
__device__ __forceinline__ void cell_upd(float ai, float af, float ag, float ao,
                                         float& c, float& h) {
    const float K1 = 1.4426950408889634f;
    float ei = ex2(fminf(-K1 * ai, 60.0f));
    float ef = ex2(fminf(-K1 * af, 60.0f));
    float eg = ex2(fminf(-2.0f * K1 * ag, 60.0f));
    float eo = ex2(fminf(-K1 * ao, 60.0f));
    float di = 1.0f + ei, df = 1.0f + ef, dg = 1.0f + eg, dn = 1.0f + eo;
    float r1 = rcp_(di * df);
    float si = df * r1;                                  // sigmoid(ai)
    float sf = di * r1;                                  // sigmoid(af)
    float r2 = rcp_(dg * dn);
    float tg = __builtin_fmaf(2.0f * dn, r2, -1.0f);     // tanh(ag)
    float so = dg * r2;                                  // sigmoid(ao)
    c = sf * c + si * tg;
    float ec = ex2(fminf(-2.0f * K1 * c, 60.0f));
    h = so * __builtin_fmaf(2.0f, rcp_(1.0f + ec), -1.0f);
}

// ws: [0 .. 2048) packed layer0 gate table: float4{i,f,g,o}[voc][hcol]
//     [2048 .. 2304) bih1+bhh1 (gate index 64q+c)
__global__ void precompute_kernel(const float* __restrict__ emb,
                                  const float* __restrict__ Wih0,
                                  const float* __restrict__ bih0,
                                  const float* __restrict__ bhh0,
                                  const float* __restrict__ bih1,
                                  const float* __restrict__ bhh1,
                                  float* __restrict__ ws) {
    int g = threadIdx.x;
    int v = blockIdx.x;
    if (v < VOC) {
        float acc = bih0[g] + bhh0[g];
        #pragma unroll
        for (int e = 0; e < EDIM; ++e)
            acc += Wih0[g * EDIM + e] * emb[v * EDIM + e];
        const int q = g >> 6, c = g & 63;
        ws[(v * 64 + c) * 4 + q] = acc;
    } else {
        ws[VOC * G4 + g] = bih1[g] + bhh1[g];
    }
}

// h LDS layout = A-fragment order for mfma_f32_16x16x32_f16 (validated R4/R7):
__device__ __forceinline__ f16x8 read_h_frag(const _Float16* hb, int kc, int l) {
    int off = kc * 512 + ((l * 8) ^ ((l & 3) << 7));
    return *(const f16x8*)(hb + off);
}
__device__ __forceinline__ void write_h(_Float16* hb, int r, int c, float v) {
    int off = (c >> 5) * 512 +
              (((((c & 31) >> 3) * 128) + r * 8 + (c & 7)) ^ ((r & 3) << 7));
    hb[off] = (_Float16)v;
}

__global__ __launch_bounds__(NT, 4)   // 4 waves/SIMD min -> 2 blocks/CU co-resident
void lstm_kernel(const int*   __restrict__ x,
                 const float* __restrict__ Whh0,
                 const float* __restrict__ Wih1,
                 const float* __restrict__ Whh1,
                 const float* __restrict__ Wfc,
                 const float* __restrict__ bfc,
                 const float* __restrict__ ws,
                 float* __restrict__ out) {
    __shared__ float4    stbl4[VOC * 64];        // 8 KB packed gate table
    __shared__ int       sxl[SEQB * Tlen];       // 4 KB tokens [seq][t]
    __shared__ _Float16  hbuf[2][2][1024];       // 8 KB [buf][layer]; rows {0,4} live
    __shared__ float     sh1f[SEQB][HDIM + 1];   // final h1, fp32

    const int tid  = threadIdx.x;
    const int b0   = blockIdx.x * SEQB;
    const int l    = tid & 63;
    const int wid  = tid >> 6;
    const bool isL1 = (wid >= 4);
    const int w    = wid & 3;                    // col block: cols [16w,16w+16)
    const int l15  = l & 15;
    const int kb   = (l >> 4) * 8;
    const int cq0  = 16 * w + l15;               // this lane's hidden col
    const int s    = l >> 4;                     // lane's nominal seq slot (0..3)
    const bool sv  = (s < SEQB);                 // lanes with a real sequence
    const int se   = sv ? s : (SEQB - 1);        // clamped seq for safe indexing
    const int r4   = 4 * s;                      // seq's A/D row (0,4)

    for (int i = tid; i < VOC * 64; i += NT)
        stbl4[i] = ((const float4*)ws)[i];
    for (int i = tid; i < SEQB * Tlen; i += NT)
        sxl[i] = x[b0 * Tlen + i];
    for (int i = tid; i < 2 * 2 * 1024; i += NT)
        ((_Float16*)hbuf)[i] = (_Float16)0.0f;

    // loop-invariant weight B-fragments: lane holds W[col=64q+16w+l15][kc*32+kb+i]
    f16x8 wA0[4], wA1[4], wI0[4], wI1[4], wH0[4], wH1[4];
    float b1s[4];
    if (!isL1) {
        #pragma unroll
        for (int q = 0; q < 4; ++q) {
            const int cq = 64 * q + cq0;
            const float* p0 = Whh0 + cq * HDIM + kb;
            const float* p1 = Whh0 + cq * HDIM + 32 + kb;
            #pragma unroll
            for (int i = 0; i < 8; ++i) { wA0[q][i] = (_Float16)p0[i]; wA1[q][i] = (_Float16)p1[i]; }
        }
    } else {
        #pragma unroll
        for (int q = 0; q < 4; ++q) {
            const int cq = 64 * q + cq0;
            b1s[q] = ws[VOC * G4 + cq];
            const float* pi0 = Wih1 + cq * HDIM + kb;
            const float* pi1 = Wih1 + cq * HDIM + 32 + kb;
            const float* ph0 = Whh1 + cq * HDIM + kb;
            const float* ph1 = Whh1 + cq * HDIM + 32 + kb;
            #pragma unroll
            for (int i = 0; i < 8; ++i) {
                wI0[q][i] = (_Float16)pi0[i]; wI1[q][i] = (_Float16)pi1[i];
                wH0[q][i] = (_Float16)ph0[i]; wH1[q][i] = (_Float16)ph1[i];
            }
        }
    }

    float cst = 0.0f;            // cell state for (seq se, col cq0)
    __syncthreads();

    int tc = 0;
    if (!isL1) tc = sxl[se * Tlen];   // token for step 0 (clamped seq slot)

    // iter k: layer0 step t=k, layer1 step t=k-1; one barrier/step
    #pragma unroll 1
    for (int k = 0; k <= Tlen; ++k) {
        const int cur = k & 1, nxt = cur ^ 1;
        const _Float16* h0b = hbuf[cur][0];
        f16x8 a0 = read_h_frag(h0b, 0, l);
        f16x8 a1 = read_h_frag(h0b, 1, l);

        if (!isL1) {
            f32x4 tq = *(const f32x4*)&stbl4[tc * 64 + cq0];   // issue gather early
            f32x4 acc0 = (f32x4)(0.0f), acc1 = (f32x4)(0.0f);
            f32x4 acc2 = (f32x4)(0.0f), acc3 = (f32x4)(0.0f);
            acc0 = __builtin_amdgcn_mfma_f32_16x16x32_f16(a0, wA0[0], acc0, 0, 0, 0);
            acc1 = __builtin_amdgcn_mfma_f32_16x16x32_f16(a0, wA0[1], acc1, 0, 0, 0);
            acc2 = __builtin_amdgcn_mfma_f32_16x16x32_f16(a0, wA0[2], acc2, 0, 0, 0);
            acc3 = __builtin_amdgcn_mfma_f32_16x16x32_f16(a0, wA0[3], acc3, 0, 0, 0);
            acc0 = __builtin_amdgcn_mfma_f32_16x16x32_f16(a1, wA1[0], acc0, 0, 0, 0);
            acc1 = __builtin_amdgcn_mfma_f32_16x16x32_f16(a1, wA1[1], acc1, 0, 0, 0);
            acc2 = __builtin_amdgcn_mfma_f32_16x16x32_f16(a1, wA1[2], acc2, 0, 0, 0);
            acc3 = __builtin_amdgcn_mfma_f32_16x16x32_f16(a1, wA1[3], acc3, 0, 0, 0);

            const int kn = (k + 1 < Tlen) ? (k + 1) : (Tlen - 1);
            const int tnext = sxl[se * Tlen + kn];              // prefetch next token

            if (k < Tlen) {
                // D reg 0 = row 4s = this lane's (seq, col): no redistribution
                float ai = acc0[0] + tq[0];
                float af = acc1[0] + tq[1];
                float ag = acc2[0] + tq[2];
                float ao = acc3[0] + tq[3];
                float hv;
                cell_upd(ai, af, ag, ao, cst, hv);
                if (sv) write_h(hbuf[nxt][0], r4, cq0, hv);
            }
            tc = tnext;
        } else {
            const _Float16* h1b = hbuf[cur][1];
            f16x8 b0f = read_h_frag(h1b, 0, l);
            f16x8 b1f = read_h_frag(h1b, 1, l);
            f32x4 acc0 = (f32x4)(0.0f), acc1 = (f32x4)(0.0f);
            f32x4 acc2 = (f32x4)(0.0f), acc3 = (f32x4)(0.0f);
            acc0 = __builtin_amdgcn_mfma_f32_16x16x32_f16(a0,  wI0[0], acc0, 0, 0, 0);
            acc1 = __builtin_amdgcn_mfma_f32_16x16x32_f16(a0,  wI0[1], acc1, 0, 0, 0);
            acc2 = __builtin_amdgcn_mfma_f32_16x16x32_f16(a0,  wI0[2], acc2, 0, 0, 0);
            acc3 = __builtin_amdgcn_mfma_f32_16x16x32_f16(a0,  wI0[3], acc3, 0, 0, 0);
            acc0 = __builtin_amdgcn_mfma_f32_16x16x32_f16(a1,  wI1[0], acc0, 0, 0, 0);
            acc1 = __builtin_amdgcn_mfma_f32_16x16x32_f16(a1,  wI1[1], acc1, 0, 0, 0);
            acc2 = __builtin_amdgcn_mfma_f32_16x16x32_f16(a1,  wI1[2], acc2, 0, 0, 0);
            acc3 = __builtin_amdgcn_mfma_f32_16x16x32_f16(a1,  wI1[3], acc3, 0, 0, 0);
            acc0 = __builtin_amdgcn_mfma_f32_16x16x32_f16(b0f, wH0[0], acc0, 0, 0, 0);
            acc1 = __builtin_amdgcn_mfma_f32_16x16x32_f16(b0f, wH0[1], acc1, 0, 0, 0);
            acc2 = __builtin_amdgcn_mfma_f32_16x16x32_f16(b0f, wH0[2], acc2, 0, 0, 0);
            acc3 = __builtin_amdgcn_mfma_f32_16x16x32_f16(b0f, wH0[3], acc3, 0, 0, 0);
            acc0 = __builtin_amdgcn_mfma_f32_16x16x32_f16(b1f, wH1[0], acc0, 0, 0, 0);
            acc1 = __builtin_amdgcn_mfma_f32_16x16x32_f16(b1f, wH1[1], acc1, 0, 0, 0);
            acc2 = __builtin_amdgcn_mfma_f32_16x16x32_f16(b1f, wH1[2], acc2, 0, 0, 0);
            acc3 = __builtin_amdgcn_mfma_f32_16x16x32_f16(b1f, wH1[3], acc3, 0, 0, 0);

            if (k >= 1) {
                float ai = acc0[0] + b1s[0];
                float af = acc1[0] + b1s[1];
                float ag = acc2[0] + b1s[2];
                float ao = acc3[0] + b1s[3];
                float hv;
                cell_upd(ai, af, ag, ao, cst, hv);
                if (sv) {
                    if (k == Tlen) sh1f[s][cq0] = hv;    // final h1 in fp32
                    else           write_h(hbuf[nxt][1], r4, cq0, hv);
                }
            }
        }
        __syncthreads();
    }

    // logits = h1(T-1) @ Wfc^T + bfc  (fp32)
    if (tid < SEQB * VOC) {
        const int seq = tid >> 3, v = tid & 7;
        float acc2 = bfc[v];
        #pragma unroll
        for (int j = 0; j < HDIM; ++j)
            acc2 += Wfc[v * HDIM + j] * sh1f[seq][j];
        out[(b0 + seq) * VOC + v] = acc2;
    }
}

extern "C" void kernel_launch(void* const* d_in, const int* in_sizes, int n_in,
                              void* d_out, int out_size, void* d_ws, size_t ws_size,
                              hipStream_t stream) {
    const int*   x    = (const int*)  d_in[0];
    const float* emb  = (const float*)d_in[1];
    const float* Wih0 = (const float*)d_in[2];
    const float* Whh0 = (const float*)d_in[3];
    const float* bih0 = (const float*)d_in[4];
    const float* bhh0 = (const float*)d_in[5];
    const float* Wih1 = (const float*)d_in[6];
    const float* Whh1 = (const float*)d_in[7];
    const float* bih1 = (const float*)d_in[8];
    const float* bhh1 = (const float*)d_in[9];
    const float* Wfc  = (const float*)d_in[10];
    const float* bfc  = (const float*)d_in[11];
    float* out = (float*)d_out;
    float* ws  = (float*)d_ws;

    hipLaunchKernelGGL(precompute_kernel, dim3(VOC + 1), dim3(G4), 0, stream,
                       emb, Wih0, bih0, bhh0, bih1, bhh1, ws);
    hipLaunchKernelGGL(lstm_kernel, dim3(NBLK), dim3(NT), 0, stream,
                       x, Whh0, Wih1, Whh1, Wfc, bfc, ws, out);
}

// Round 11
// 231.594 us; speedup vs baseline: 12.3157x; 1.6136x over previous
//
#include <hip/hip_runtime.h>

#define Bsz   1024
#define Tlen  512
#define VOC   8
#define EDIM  32
#define HDIM  64
#define G4    256
#define SEQB  4                  // sequences per block, A-rows {0,4,8,12}
#define NT    768                // 12 waves: 0-3 L0, 4-7 L1-I, 8-11 L1-H
#define NBLK  (Bsz / SEQB)       // 256 blocks -> all 256 CUs

typedef _Float16 f16x8 __attribute__((ext_vector_type(8)));
typedef float    f32x4 __attribute__((ext_vector_type(4)));

__device__ __forceinline__ float ex2(float x) {
#if __has_builtin(__builtin_amdgcn_exp2f)
    return __builtin_amdgcn_exp2f(x);
#else
    return exp2f(x);
#endif
}
__device__ __forceinline__ float rcp_(float x) {
#if __has_builtin(__builtin_amdgcn_rcpf)
    return __builtin_amdgcn_rcpf(x);
#else
    return 1.0f / x;
#endif
}

// paired-rcp LSTM cell update (identical numerics to R6/R7): 5 exp2 + 3 rcp
__device__ __forceinline__ void cell_upd(float ai, float af, float ag, float ao,
                                         float& c, float& h) {
    const float K1 = 1.4426950408889634f;
    float ei = ex2(fminf(-K1 * ai, 60.0f));
    float ef = ex2(fminf(-K1 * af, 60.0f));
    float eg = ex2(fminf(-2.0f * K1 * ag, 60.0f));
    float eo = ex2(fminf(-K1 * ao, 60.0f));
    float di = 1.0f + ei, df = 1.0f + ef, dg = 1.0f + eg, dn = 1.0f + eo;
    float r1 = rcp_(di * df);
    float si = df * r1;                                  // sigmoid(ai)
    float sf = di * r1;                                  // sigmoid(af)
    float r2 = rcp_(dg * dn);
    float tg = __builtin_fmaf(2.0f * dn, r2, -1.0f);     // tanh(ag)
    float so = dg * r2;                                  // sigmoid(ao)
    c = sf * c + si * tg;
    float ec = ex2(fminf(-2.0f * K1 * c, 60.0f));
    h = so * __builtin_fmaf(2.0f, rcp_(1.0f + ec), -1.0f);
}

// ws: [0 .. 2048) packed layer0 gate table: float4{i,f,g,o}[voc][hcol]
//     [2048 .. 2304) bih1+bhh1 (gate index 64q+c)
__global__ void precompute_kernel(const float* __restrict__ emb,
                                  const float* __restrict__ Wih0,
                                  const float* __restrict__ bih0,
                                  const float* __restrict__ bhh0,
                                  const float* __restrict__ bih1,
                                  const float* __restrict__ bhh1,
                                  float* __restrict__ ws) {
    int g = threadIdx.x;
    int v = blockIdx.x;
    if (v < VOC) {
        float acc = bih0[g] + bhh0[g];
        #pragma unroll
        for (int e = 0; e < EDIM; ++e)
            acc += Wih0[g * EDIM + e] * emb[v * EDIM + e];
        const int q = g >> 6, c = g & 63;
        ws[(v * 64 + c) * 4 + q] = acc;
    } else {
        ws[VOC * G4 + g] = bih1[g] + bhh1[g];
    }
}

// h LDS layout = A-fragment order for mfma_f32_16x16x32_f16 (validated R4/R7):
__device__ __forceinline__ f16x8 read_h_frag(const _Float16* hb, int kc, int l) {
    int off = kc * 512 + ((l * 8) ^ ((l & 3) << 7));
    return *(const f16x8*)(hb + off);
}
__device__ __forceinline__ void write_h(_Float16* hb, int r, int c, float v) {
    int off = (c >> 5) * 512 +
              (((((c & 31) >> 3) * 128) + r * 8 + (c & 7)) ^ ((r & 3) << 7));
    hb[off] = (_Float16)v;
}

__global__ __launch_bounds__(NT)
void lstm_kernel(const int*   __restrict__ x,
                 const float* __restrict__ Whh0,
                 const float* __restrict__ Wih1,
                 const float* __restrict__ Whh1,
                 const float* __restrict__ Wfc,
                 const float* __restrict__ bfc,
                 const float* __restrict__ ws,
                 float* __restrict__ out) {
    __shared__ float4    stbl4[VOC * 64];        // 8 KB packed gate table
    __shared__ int       sxl[SEQB * Tlen];       // 8 KB tokens [seq][t]
    __shared__ _Float16  h0buf[2][1024];         // 4 KB h0 double buffer (slot t&1 = h0(t))
    __shared__ _Float16  h1buf[2][1024];         // 4 KB h1 double buffer (slot t&1 = h1(t))
    __shared__ float     pbuf[2][4][64][4];      // 8 KB I-GEMM partials [buf][colblk][lane][quad]
    __shared__ float     sh1f[SEQB][HDIM + 1];   // final h1, fp32

    const int tid  = threadIdx.x;
    const int b0   = blockIdx.x * SEQB;
    const int l    = tid & 63;
    const int wid  = tid >> 6;                   // 0..11
    const int role = (wid < 4) ? 0 : ((wid < 8) ? 1 : 2);   // 0=L0, 1=L1-I, 2=L1-H
    const int w    = wid & 3;                    // col block: cols [16w,16w+16)
    const int l15  = l & 15;
    const int kb   = (l >> 4) * 8;
    const int cq0  = 16 * w + l15;               // this lane's hidden col
    const int s    = l >> 4;                     // lane's seq (0..3) -> A/D row 4s
    const int r4   = 4 * s;

    for (int i = tid; i < VOC * 64; i += NT)
        stbl4[i] = ((const float4*)ws)[i];
    for (int i = tid; i < SEQB * Tlen; i += NT)
        sxl[i] = x[b0 * Tlen + i];
    for (int i = tid; i < 2 * 1024; i += NT) {
        ((_Float16*)h0buf)[i] = (_Float16)0.0f;
        ((_Float16*)h1buf)[i] = (_Float16)0.0f;
    }

    // all roles use the same fragment geometry; only the weight matrix differs
    const float* wbase = (role == 0) ? Whh0 : ((role == 1) ? Wih1 : Whh1);
    f16x8 wX0[4], wX1[4];
    float b1q[4] = {0.0f, 0.0f, 0.0f, 0.0f};
    #pragma unroll
    for (int q = 0; q < 4; ++q) {
        const int cq = 64 * q + cq0;
        const float* p0 = wbase + cq * HDIM + kb;
        const float* p1 = wbase + cq * HDIM + 32 + kb;
        #pragma unroll
        for (int i = 0; i < 8; ++i) { wX0[q][i] = (_Float16)p0[i]; wX1[q][i] = (_Float16)p1[i]; }
        if (role == 2) b1q[q] = ws[VOC * G4 + cq];
    }

    float cst = 0.0f;            // cell state for (seq s, col cq0) of this role's layer
    __syncthreads();

    int tc = (role == 0) ? sxl[s * Tlen] : 0;

    // iter k: L0 does step k; I does I-GEMM of step k-1; H finishes step k-2.
    // One barrier/step; all cross-wave reads are >= 1 barrier old.
    #pragma unroll 1
    for (int k = 0; k < Tlen + 2; ++k) {
        if (role == 0) {
            if (k < Tlen) {
                const _Float16* h0b = h0buf[(k + 1) & 1];       // h0(k-1)
                f16x8 a0 = read_h_frag(h0b, 0, l);
                f16x8 a1 = read_h_frag(h0b, 1, l);
                f32x4 tq = *(const f32x4*)&stbl4[tc * 64 + cq0]; // gather early
                f32x4 acc0 = (f32x4)(0.0f), acc1 = (f32x4)(0.0f);
                f32x4 acc2 = (f32x4)(0.0f), acc3 = (f32x4)(0.0f);
                acc0 = __builtin_amdgcn_mfma_f32_16x16x32_f16(a0, wX0[0], acc0, 0, 0, 0);
                acc1 = __builtin_amdgcn_mfma_f32_16x16x32_f16(a0, wX0[1], acc1, 0, 0, 0);
                acc2 = __builtin_amdgcn_mfma_f32_16x16x32_f16(a0, wX0[2], acc2, 0, 0, 0);
                acc3 = __builtin_amdgcn_mfma_f32_16x16x32_f16(a0, wX0[3], acc3, 0, 0, 0);
                acc0 = __builtin_amdgcn_mfma_f32_16x16x32_f16(a1, wX1[0], acc0, 0, 0, 0);
                acc1 = __builtin_amdgcn_mfma_f32_16x16x32_f16(a1, wX1[1], acc1, 0, 0, 0);
                acc2 = __builtin_amdgcn_mfma_f32_16x16x32_f16(a1, wX1[2], acc2, 0, 0, 0);
                acc3 = __builtin_amdgcn_mfma_f32_16x16x32_f16(a1, wX1[3], acc3, 0, 0, 0);

                const int kn = (k + 1 < Tlen) ? (k + 1) : (Tlen - 1);
                const int tnext = sxl[s * Tlen + kn];

                float ai = acc0[0] + tq[0];
                float af = acc1[0] + tq[1];
                float ag = acc2[0] + tq[2];
                float ao = acc3[0] + tq[3];
                float hv;
                cell_upd(ai, af, ag, ao, cst, hv);
                write_h(h0buf[k & 1], r4, cq0, hv);
                tc = tnext;
            }
        } else if (role == 1) {
            if (k >= 1 && k <= Tlen) {
                const int t = k - 1;                            // I-GEMM for step t
                const _Float16* h0b = h0buf[t & 1];             // h0(t), written last iter
                f16x8 a0 = read_h_frag(h0b, 0, l);
                f16x8 a1 = read_h_frag(h0b, 1, l);
                f32x4 acc0 = (f32x4)(0.0f), acc1 = (f32x4)(0.0f);
                f32x4 acc2 = (f32x4)(0.0f), acc3 = (f32x4)(0.0f);
                acc0 = __builtin_amdgcn_mfma_f32_16x16x32_f16(a0, wX0[0], acc0, 0, 0, 0);
                acc1 = __builtin_amdgcn_mfma_f32_16x16x32_f16(a0, wX0[1], acc1, 0, 0, 0);
                acc2 = __builtin_amdgcn_mfma_f32_16x16x32_f16(a0, wX0[2], acc2, 0, 0, 0);
                acc3 = __builtin_amdgcn_mfma_f32_16x16x32_f16(a0, wX0[3], acc3, 0, 0, 0);
                acc0 = __builtin_amdgcn_mfma_f32_16x16x32_f16(a1, wX1[0], acc0, 0, 0, 0);
                acc1 = __builtin_amdgcn_mfma_f32_16x16x32_f16(a1, wX1[1], acc1, 0, 0, 0);
                acc2 = __builtin_amdgcn_mfma_f32_16x16x32_f16(a1, wX1[2], acc2, 0, 0, 0);
                acc3 = __builtin_amdgcn_mfma_f32_16x16x32_f16(a1, wX1[3], acc3, 0, 0, 0);
                f32x4 pv = {acc0[0], acc1[0], acc2[0], acc3[0]};
                *(f32x4*)&pbuf[t & 1][w][l][0] = pv;            // partial for H at iter k+1
            }
        } else {
            if (k >= 2) {
                const int t = k - 2;                            // finish layer-1 step t
                const _Float16* h1b = h1buf[(t + 1) & 1];       // h1(t-1)
                f16x8 b0f = read_h_frag(h1b, 0, l);
                f16x8 b1f = read_h_frag(h1b, 1, l);
                f32x4 acc0 = (f32x4)(0.0f), acc1 = (f32x4)(0.0f);
                f32x4 acc2 = (f32x4)(0.0f), acc3 = (f32x4)(0.0f);
                acc0 = __builtin_amdgcn_mfma_f32_16x16x32_f16(b0f, wX0[0], acc0, 0, 0, 0);
                acc1 = __builtin_amdgcn_mfma_f32_16x16x32_f16(b0f, wX0[1], acc1, 0, 0, 0);
                acc2 = __builtin_amdgcn_mfma_f32_16x16x32_f16(b0f, wX0[2], acc2, 0, 0, 0);
                acc3 = __builtin_amdgcn_mfma_f32_16x16x32_f16(b0f, wX0[3], acc3, 0, 0, 0);
                acc0 = __builtin_amdgcn_mfma_f32_16x16x32_f16(b1f, wX1[0], acc0, 0, 0, 0);
                acc1 = __builtin_amdgcn_mfma_f32_16x16x32_f16(b1f, wX1[1], acc1, 0, 0, 0);
                acc2 = __builtin_amdgcn_mfma_f32_16x16x32_f16(b1f, wX1[2], acc2, 0, 0, 0);
                acc3 = __builtin_amdgcn_mfma_f32_16x16x32_f16(b1f, wX1[3], acc3, 0, 0, 0);
                f32x4 pv = *(const f32x4*)&pbuf[t & 1][w][l][0]; // I(t), written iter k-1
                float ai = acc0[0] + pv[0] + b1q[0];
                float af = acc1[0] + pv[1] + b1q[1];
                float ag = acc2[0] + pv[2] + b1q[2];
                float ao = acc3[0] + pv[3] + b1q[3];
                float hv;
                cell_upd(ai, af, ag, ao, cst, hv);
                if (t == Tlen - 1) sh1f[s][cq0] = hv;           // final h1 in fp32
                else               write_h(h1buf[t & 1], r4, cq0, hv);
            }
        }
        __syncthreads();
    }

    // logits = h1(T-1) @ Wfc^T + bfc  (fp32)
    if (tid < SEQB * VOC) {
        const int seq = tid >> 3, v = tid & 7;
        float acc2 = bfc[v];
        #pragma unroll
        for (int j = 0; j < HDIM; ++j)
            acc2 += Wfc[v * HDIM + j] * sh1f[seq][j];
        out[(b0 + seq) * VOC + v] = acc2;
    }
}

extern "C" void kernel_launch(void* const* d_in, const int* in_sizes, int n_in,
                              void* d_out, int out_size, void* d_ws, size_t ws_size,
                              hipStream_t stream) {
    const int*   x    = (const int*)  d_in[0];
    const float* emb  = (const float*)d_in[1];
    const float* Wih0 = (const float*)d_in[2];
    const float* Whh0 = (const float*)d_in[3];
    const float* bih0 = (const float*)d_in[4];
    const float* bhh0 = (const float*)d_in[5];
    const float* Wih1 = (const float*)d_in[6];
    const float* Whh1 = (const float*)d_in[7];
    const float* bih1 = (const float*)d_in[8];
    const float* bhh1 = (const float*)d_in[9];
    const float* Wfc  = (const float*)d_in[10];
    const float* bfc  = (const float*)d_in[11];
    float* out = (float*)d_out;
    float* ws  = (float*)d_ws;

    hipLaunchKernelGGL(precompute_kernel, dim3(VOC + 1), dim3(G4), 0, stream,
                       emb, Wih0, bih0, bhh0, bih1, bhh1, ws);
    hipLaunchKernelGGL(lstm_kernel, dim3(NBLK), dim3(NT), 0, stream,
                       x, Whh0, Wih1, Whh1, Wfc, bfc, ws, out);
}

// Round 12
// 213.133 us; speedup vs baseline: 13.3824x; 1.0866x over previous
//
#include <hip/hip_runtime.h>

#define Bsz   1024
#define Tlen  512
#define VOC   8
#define EDIM  32
#define HDIM  64
#define G4    256
#define SEQB  4                  // sequences per block
#define NT    512                // 8 waves: 0-3 L0, 4-7 L1
#define NBLK  (Bsz / SEQB)       // 256 blocks -> all 256 CUs
#define ITERS 520                // Tlen + 5 lag + pad to multiple of 4

typedef _Float16 f16x8 __attribute__((ext_vector_type(8)));
typedef float    f32x4 __attribute__((ext_vector_type(4)));

__device__ __forceinline__ float ex2(float x) {
#if __has_builtin(__builtin_amdgcn_exp2f)
    return __builtin_amdgcn_exp2f(x);
#else
    return exp2f(x);
#endif
}
__device__ __forceinline__ float rcp_(float x) {
#if __has_builtin(__builtin_amdgcn_rcpf)
    return __builtin_amdgcn_rcpf(x);
#else
    return 1.0f / x;
#endif
}

// paired-rcp LSTM cell update (identical numerics to R6/R7): 5 exp2 + 3 rcp
__device__ __forceinline__ void cell_upd(float ai, float af, float ag, float ao,
                                         float& c, float& h) {
    const float K1 = 1.4426950408889634f;
    float ei = ex2(fminf(-K1 * ai, 60.0f));
    float ef = ex2(fminf(-K1 * af, 60.0f));
    float eg = ex2(fminf(-2.0f * K1 * ag, 60.0f));
    float eo = ex2(fminf(-K1 * ao, 60.0f));
    float di = 1.0f + ei, df = 1.0f + ef, dg = 1.0f + eg, dn = 1.0f + eo;
    float r1 = rcp_(di * df);
    float si = df * r1;                                  // sigmoid(ai)
    float sf = di * r1;                                  // sigmoid(af)
    float r2 = rcp_(dg * dn);
    float tg = __builtin_fmaf(2.0f * dn, r2, -1.0f);     // tanh(ag)
    float so = dg * r2;                                  // sigmoid(ao)
    c = sf * c + si * tg;
    float ec = ex2(fminf(-2.0f * K1 * c, 60.0f));
    h = so * __builtin_fmaf(2.0f, rcp_(1.0f + ec), -1.0f);
}

// ws: [0 .. 2048) packed layer0 gate table: float4{i,f,g,o}[voc][hcol]
//     [2048 .. 2304) bih1+bhh1 (gate index 64q+c)
__global__ void precompute_kernel(const float* __restrict__ emb,
                                  const float* __restrict__ Wih0,
                                  const float* __restrict__ bih0,
                                  const float* __restrict__ bhh0,
                                  const float* __restrict__ bih1,
                                  const float* __restrict__ bhh1,
                                  float* __restrict__ ws) {
    int g = threadIdx.x;
    int v = blockIdx.x;
    if (v < VOC) {
        float acc = bih0[g] + bhh0[g];
        #pragma unroll
        for (int e = 0; e < EDIM; ++e)
            acc += Wih0[g * EDIM + e] * emb[v * EDIM + e];
        const int q = g >> 6, c = g & 63;
        ws[(v * 64 + c) * 4 + q] = acc;
    } else {
        ws[VOC * G4 + g] = bih1[g] + bhh1[g];
    }
}

// h LDS layout = A-fragment order for mfma_f32_16x16x32_f16 (validated R4/R7):
__device__ __forceinline__ f16x8 read_h_frag(const _Float16* hb, int kc, int l) {
    int off = kc * 512 + ((l * 8) ^ ((l & 3) << 7));
    return *(const f16x8*)(hb + off);
}
__device__ __forceinline__ void write_h(_Float16* hb, int r, int c, float v) {
    int off = (c >> 5) * 512 +
              (((((c & 31) >> 3) * 128) + r * 8 + (c & 7)) ^ ((r & 3) << 7));
    hb[off] = (_Float16)v;
}

#define MFMA8(A0, A1, W0, W1, C0, C1, C2, C3)                                   \
    C0 = __builtin_amdgcn_mfma_f32_16x16x32_f16(A0, W0[0], C0, 0, 0, 0);        \
    C1 = __builtin_amdgcn_mfma_f32_16x16x32_f16(A0, W0[1], C1, 0, 0, 0);        \
    C2 = __builtin_amdgcn_mfma_f32_16x16x32_f16(A0, W0[2], C2, 0, 0, 0);        \
    C3 = __builtin_amdgcn_mfma_f32_16x16x32_f16(A0, W0[3], C3, 0, 0, 0);        \
    C0 = __builtin_amdgcn_mfma_f32_16x16x32_f16(A1, W1[0], C0, 0, 0, 0);        \
    C1 = __builtin_amdgcn_mfma_f32_16x16x32_f16(A1, W1[1], C1, 0, 0, 0);        \
    C2 = __builtin_amdgcn_mfma_f32_16x16x32_f16(A1, W1[2], C2, 0, 0, 0);        \
    C3 = __builtin_amdgcn_mfma_f32_16x16x32_f16(A1, W1[3], C3, 0, 0, 0);

__global__ __launch_bounds__(NT)
void lstm_kernel(const int*   __restrict__ x,
                 const float* __restrict__ Whh0,
                 const float* __restrict__ Wih1,
                 const float* __restrict__ Whh1,
                 const float* __restrict__ Wfc,
                 const float* __restrict__ bfc,
                 const float* __restrict__ ws,
                 float* __restrict__ out) {
    __shared__ float4    stbl4[VOC * 64];        // 8 KB packed gate table
    __shared__ int       sxl[SEQB * Tlen];       // 8 KB tokens [seq][t]
    __shared__ _Float16  bbuf[2][1024];          // 4 KB batched-h0 A-frag ping-pong
                                                 //   group g=(t>>2) -> buf g&1; h0(t) at row 4s+(t&3)
    __shared__ _Float16  h1buf[2][1024];         // 4 KB h1 double buffer (rows 4s)
    __shared__ float     pbuf[2][4][4][4][64];   // 32 KB I-partials [grp&1][t&3][w][gate][lane]
    __shared__ float     sh1f[SEQB][HDIM + 1];   // final h1, fp32

    const int tid  = threadIdx.x;
    const int b0   = blockIdx.x * SEQB;
    const int l    = tid & 63;
    const int wid  = tid >> 6;
    const bool isL1 = (wid >= 4);
    const int w    = wid & 3;                    // col block: cols [16w,16w+16)
    const int l15  = l & 15;
    const int kbq  = (l >> 4) * 8;
    const int cq0  = 16 * w + l15;               // this lane's hidden col
    const int s    = l >> 4;                     // lane's seq (0..3)
    const int r4   = 4 * s;

    for (int i = tid; i < VOC * 64; i += NT)
        stbl4[i] = ((const float4*)ws)[i];
    for (int i = tid; i < SEQB * Tlen; i += NT)
        sxl[i] = x[b0 * Tlen + i];
    for (int i = tid; i < 2 * 1024; i += NT) {
        ((_Float16*)bbuf)[i]  = (_Float16)0.0f;
        ((_Float16*)h1buf)[i] = (_Float16)0.0f;
    }

    // loop-invariant weight B-fragments: lane holds W[col=64q+16w+l15][kc*32+kbq+i]
    f16x8 wA0[4], wA1[4], wI0[4], wI1[4], wH0[4], wH1[4];
    float b1q[4] = {0.0f, 0.0f, 0.0f, 0.0f};
    if (!isL1) {
        #pragma unroll
        for (int q = 0; q < 4; ++q) {
            const int cq = 64 * q + cq0;
            const float* p0 = Whh0 + cq * HDIM + kbq;
            const float* p1 = Whh0 + cq * HDIM + 32 + kbq;
            #pragma unroll
            for (int i = 0; i < 8; ++i) { wA0[q][i] = (_Float16)p0[i]; wA1[q][i] = (_Float16)p1[i]; }
        }
    } else {
        #pragma unroll
        for (int q = 0; q < 4; ++q) {
            const int cq = 64 * q + cq0;
            b1q[q] = ws[VOC * G4 + cq];
            const float* pi0 = Wih1 + cq * HDIM + kbq;
            const float* pi1 = Wih1 + cq * HDIM + 32 + kbq;
            const float* ph0 = Whh1 + cq * HDIM + kbq;
            const float* ph1 = Whh1 + cq * HDIM + 32 + kbq;
            #pragma unroll
            for (int i = 0; i < 8; ++i) {
                wI0[q][i] = (_Float16)pi0[i]; wI1[q][i] = (_Float16)pi1[i];
                wH0[q][i] = (_Float16)ph0[i]; wH1[q][i] = (_Float16)ph1[i];
            }
        }
    }

    float cst = 0.0f;            // cell state for (seq s, col cq0) of this role's layer
    __syncthreads();

    int tc = isL1 ? 0 : sxl[s * Tlen];

// One unrolled body; J is a compile-time literal (0..3) so all acc-reg
// indices are static (rule #20). k = kb + J.
// L0: step k. reads h0(k-1) = bbuf[((k+7)>>2)&1] reg (J+3)&3; writes bbuf[(k>>2)&1] row 4s+J.
// L1: at J==0, k>=4: batched I-GEMM for steps k-4..k-1 from bbuf[((k>>2)+1)&1] -> pbuf.
//     H-finish for t=k-5 (t&3 = (J+3)&3 static): h1 recurrence + pbuf + bias.
#define BODY(J)                                                                  \
    {                                                                            \
        const int k = kb + (J);                                                  \
        if (!isL1) {                                                             \
            if (k < Tlen) {                                                      \
                const _Float16* rb = bbuf[((k + 7) >> 2) & 1];                   \
                f16x8 a0 = read_h_frag(rb, 0, l);                                \
                f16x8 a1 = read_h_frag(rb, 1, l);                                \
                f32x4 tq = *(const f32x4*)&stbl4[tc * 64 + cq0];                 \
                f32x4 c0 = (f32x4)(0.0f), c1 = (f32x4)(0.0f);                    \
                f32x4 c2 = (f32x4)(0.0f), c3 = (f32x4)(0.0f);                    \
                MFMA8(a0, a1, wA0, wA1, c0, c1, c2, c3)                          \
                const int kn = (k + 1 < Tlen) ? (k + 1) : (Tlen - 1);            \
                const int tnext = sxl[s * Tlen + kn];                            \
                const int J0 = ((J) + 3) & 3;                                    \
                float ai = c0[J0] + tq[0];                                       \
                float af = c1[J0] + tq[1];                                       \
                float ag = c2[J0] + tq[2];                                       \
                float ao = c3[J0] + tq[3];                                       \
                float hv;                                                        \
                cell_upd(ai, af, ag, ao, cst, hv);                               \
                write_h(bbuf[(k >> 2) & 1], r4 + (J), cq0, hv);                  \
                tc = tnext;                                                      \
            }                                                                    \
        } else {                                                                 \
            if ((J) == 0 && k >= 4 && k <= Tlen) {                               \
                const int pb = ((k >> 2) + 1) & 1;                               \
                const _Float16* ib = bbuf[pb];                                   \
                f16x8 d0 = read_h_frag(ib, 0, l);                                \
                f16x8 d1 = read_h_frag(ib, 1, l);                                \
                f32x4 i0 = (f32x4)(0.0f), i1 = (f32x4)(0.0f);                    \
                f32x4 i2 = (f32x4)(0.0f), i3 = (f32x4)(0.0f);                    \
                MFMA8(d0, d1, wI0, wI1, i0, i1, i2, i3)                          \
                _Pragma("unroll")                                                \
                for (int jj = 0; jj < 4; ++jj) {                                 \
                    pbuf[pb][jj][w][0][l] = i0[jj];                              \
                    pbuf[pb][jj][w][1][l] = i1[jj];                              \
                    pbuf[pb][jj][w][2][l] = i2[jj];                              \
                    pbuf[pb][jj][w][3][l] = i3[jj];                              \
                }                                                                \
            }                                                                    \
            if (k >= 5 && k < Tlen + 5) {                                        \
                const int t = k - 5;                                             \
                const _Float16* hbp = h1buf[(t + 1) & 1];                        \
                f16x8 b0f = read_h_frag(hbp, 0, l);                              \
                f16x8 b1f = read_h_frag(hbp, 1, l);                              \
                f32x4 c0 = (f32x4)(0.0f), c1 = (f32x4)(0.0f);                    \
                f32x4 c2 = (f32x4)(0.0f), c3 = (f32x4)(0.0f);                    \
                MFMA8(b0f, b1f, wH0, wH1, c0, c1, c2, c3)                        \
                const int pr = (t >> 2) & 1;                                     \
                const int tm = ((J) + 3) & 3;                                    \
                float ai = c0[0] + pbuf[pr][tm][w][0][l] + b1q[0];               \
                float af = c1[0] + pbuf[pr][tm][w][1][l] + b1q[1];               \
                float ag = c2[0] + pbuf[pr][tm][w][2][l] + b1q[2];               \
                float ao = c3[0] + pbuf[pr][tm][w][3][l] + b1q[3];               \
                float hv;                                                        \
                cell_upd(ai, af, ag, ao, cst, hv);                               \
                if (t == Tlen - 1) sh1f[s][cq0] = hv;                            \
                else               write_h(h1buf[t & 1], r4, cq0, hv);           \
            }                                                                    \
        }                                                                        \
        __syncthreads();                                                         \
    }

    #pragma unroll 1
    for (int kb = 0; kb < ITERS; kb += 4) {
        BODY(0)
        BODY(1)
        BODY(2)
        BODY(3)
    }
#undef BODY

    // logits = h1(T-1) @ Wfc^T + bfc  (fp32)
    if (tid < SEQB * VOC) {
        const int seq = tid >> 3, v = tid & 7;
        float acc2 = bfc[v];
        #pragma unroll
        for (int j = 0; j < HDIM; ++j)
            acc2 += Wfc[v * HDIM + j] * sh1f[seq][j];
        out[(b0 + seq) * VOC + v] = acc2;
    }
}

extern "C" void kernel_launch(void* const* d_in, const int* in_sizes, int n_in,
                              void* d_out, int out_size, void* d_ws, size_t ws_size,
                              hipStream_t stream) {
    const int*   x    = (const int*)  d_in[0];
    const float* emb  = (const float*)d_in[1];
    const float* Wih0 = (const float*)d_in[2];
    const float* Whh0 = (const float*)d_in[3];
    const float* bih0 = (const float*)d_in[4];
    const float* bhh0 = (const float*)d_in[5];
    const float* Wih1 = (const float*)d_in[6];
    const float* Whh1 = (const float*)d_in[7];
    const float* bih1 = (const float*)d_in[8];
    const float* bhh1 = (const float*)d_in[9];
    const float* Wfc  = (const float*)d_in[10];
    const float* bfc  = (const float*)d_in[11];
    float* out = (float*)d_out;
    float* ws  = (float*)d_ws;

    hipLaunchKernelGGL(precompute_kernel, dim3(VOC + 1), dim3(G4), 0, stream,
                       emb, Wih0, bih0, bhh0, bih1, bhh1, ws);
    hipLaunchKernelGGL(lstm_kernel, dim3(NBLK), dim3(NT), 0, stream,
                       x, Whh0, Wih1, Whh1, Wfc, bfc, ws, out);
}